// Round 2
// 372.026 us; speedup vs baseline: 1.1307x; 1.1307x over previous
//
#include <hip/hip_runtime.h>

// BiGRU, B=512, T=512, D=16, H=64.
// Backward direction needs only ONE cell step (ys_b[0] = GRUCell(x[:,T-1,:], 0)).
//
// Structure (unchanged from 420us version): 4 waves per batch (block=256),
// K-split recurrent matvec, one barrier per step, parity double-buffered
// partials, all waves redundantly compute identical h (fixed reduce order
// => bitwise equal across waves).
//
// Round-4 diet (this version):
//  - gate reciprocals via v_rcp_f32 (__builtin_amdgcn_rcpf) instead of IEEE
//    division (v_div_scale/fmas/fixup ~9 instr + long dep chain, x3/step).
//  - xg reads prefetched one step ahead: nothing but the 12 partial reads and
//    gate math remains after the barrier.
//  - partial reduce is a 3-level add tree (was 12-deep serial +=).
//  - dual accumulators per gate (8+8) halve the FMA dependency chain.
//  - recurrence unrolled x8 with pointer bases: every ds offset is an
//    immediate; parity (S&1) is compile-time.
//  - prefetch index clamped so no access ever leaves the xg array (the
//    clamped final prefetch is dead anyway).

#define Hh 64
#define Dd 16
#define Tt 512
#define Bb 512
#define CH 64   // timesteps per LDS chunk
#define NW 4    // waves per block
#define KW 16   // k-columns per wave

__device__ __forceinline__ float rcp_fast(float v) { return __builtin_amdgcn_rcpf(v); }
__device__ __forceinline__ float sigmoid_fast(float v) {
    return rcp_fast(1.0f + __expf(-v));
}
__device__ __forceinline__ float tanh_fast(float v) {
    return 1.0f - 2.0f * rcp_fast(__expf(2.0f * v) + 1.0f);
}
__device__ __forceinline__ float lane_bcast(float v, int k) {
    return __int_as_float(__builtin_amdgcn_readlane(__float_as_int(v), k));
}
__device__ __forceinline__ float dot4(float4 a, float4 b) {
    return a.x * b.x + a.y * b.y + a.z * b.z + a.w * b.w;
}

// One recurrence step. S in [0,8): parity (S&1) and all LDS offsets are
// compile-time. Consumes prefetched xr_n/xz_n/xn_n, prefetches step S+1.
// PF = prefetch row (compile-time): min(tt+S+1, 63) - tt, kept inside xg.
#define GSTEP(S, PF) do {                                                    \
    const float xr = xr_n, xz = xz_n, xnv = xn_n;                            \
    float pr0 = 0.f, pr1 = 0.f, pz0 = 0.f, pz1 = 0.f, pn0 = 0.f, pn1 = 0.f; \
    _Pragma("unroll")                                                        \
    for (int kk = 0; kk < 8; ++kk) {                                         \
        const float ha = lane_bcast(h, k0 + kk);                             \
        const float hb = lane_bcast(h, k0 + kk + 8);                         \
        pr0 += wr[kk] * ha;   pr1 += wr[kk + 8] * hb;                        \
        pz0 += wz[kk] * ha;   pz1 += wz[kk + 8] * hb;                        \
        pn0 += wn[kk] * ha;   pn1 += wn[kk + 8] * hb;                        \
    }                                                                        \
    pw[((S)&1) * 768 +   0] = pr0 + pr1;                                     \
    pw[((S)&1) * 768 +  64] = pz0 + pz1;                                     \
    pw[((S)&1) * 768 + 128] = pn0 + pn1;                                     \
    xr_n = xgp[(PF) * Hh];                                                   \
    xz_n = xgp[CH * Hh + (PF) * Hh];                                         \
    xn_n = xgp[2 * CH * Hh + (PF) * Hh];                                     \
    __syncthreads();                                                         \
    const float q00 = prd[((S)&1) * 768 +   0];                              \
    const float q01 = prd[((S)&1) * 768 +  64];                              \
    const float q02 = prd[((S)&1) * 768 + 128];                              \
    const float q10 = prd[((S)&1) * 768 + 192];                              \
    const float q11 = prd[((S)&1) * 768 + 256];                              \
    const float q12 = prd[((S)&1) * 768 + 320];                              \
    const float q20 = prd[((S)&1) * 768 + 384];                              \
    const float q21 = prd[((S)&1) * 768 + 448];                              \
    const float q22 = prd[((S)&1) * 768 + 512];                              \
    const float q30 = prd[((S)&1) * 768 + 576];                              \
    const float q31 = prd[((S)&1) * 768 + 640];                              \
    const float q32 = prd[((S)&1) * 768 + 704];                              \
    const float ar = xr  + ((q00 + q10) + (q20 + q30));                      \
    const float az = xz  + ((q01 + q11) + (q21 + q31));                      \
    const float an = bhn + ((q02 + q12) + (q22 + q32));                      \
    const float r = sigmoid_fast(ar);                                        \
    const float z = sigmoid_fast(az);                                        \
    const float n = tanh_fast(xnv + r * an);                                 \
    h = n + z * (h - n);                                                     \
} while (0)

__global__ __launch_bounds__(256, 2)
void bigru_fused_kernel(const float* __restrict__ x,
                        const float* __restrict__ w_ih_f, const float* __restrict__ w_hh_f,
                        const float* __restrict__ b_ih_f, const float* __restrict__ b_hh_f,
                        const float* __restrict__ w_ih_b, const float* __restrict__ w_hh_b,
                        const float* __restrict__ b_ih_b, const float* __restrict__ b_hh_b,
                        const float* __restrict__ fc_w,  const float* __restrict__ fc_b,
                        float* __restrict__ out)
{
    const int tid = threadIdx.x;
    const int j   = tid & 63;            // hidden unit
    const int w   = tid >> 6;            // wave id 0..3
    const int b   = blockIdx.x;          // batch element
    const int k0  = __builtin_amdgcn_readfirstlane(w << 4);  // SGPR k-base

    __shared__ __align__(16) float xbuf[CH * Dd];        // 4 KB raw x chunk
    __shared__ __align__(16) float xg[3][CH][Hh];        // 48 KB input proj (+bias)
    __shared__ __align__(16) float parts[2][NW][3][Hh];  // 6 KB matvec partials

    // ---- recurrent weights: rows {j,64+j,128+j}, cols [k0,k0+16) -> 48 regs ----
    float wr[KW], wz[KW], wn[KW];
    {
        const float4* r0 = (const float4*)(w_hh_f + (size_t)j            * Hh + k0);
        const float4* r1 = (const float4*)(w_hh_f + (size_t)(Hh + j)     * Hh + k0);
        const float4* r2 = (const float4*)(w_hh_f + (size_t)(2 * Hh + j) * Hh + k0);
#pragma unroll
        for (int q = 0; q < KW / 4; ++q) {
            float4 a = r0[q]; wr[4*q] = a.x; wr[4*q+1] = a.y; wr[4*q+2] = a.z; wr[4*q+3] = a.w;
            float4 c = r1[q]; wz[4*q] = c.x; wz[4*q+1] = c.y; wz[4*q+2] = c.z; wz[4*q+3] = c.w;
            float4 e = r2[q]; wn[4*q] = e.x; wn[4*q+1] = e.y; wn[4*q+2] = e.z; wn[4*q+3] = e.w;
        }
    }
    // ---- input-projection weights (hoisted; 48 regs) + biases ----
    float4 wir[4], wiz[4], win[4];
    {
        const float4* p0 = (const float4*)(w_ih_f + (size_t)j            * Dd);
        const float4* p1 = (const float4*)(w_ih_f + (size_t)(Hh + j)     * Dd);
        const float4* p2 = (const float4*)(w_ih_f + (size_t)(2 * Hh + j) * Dd);
#pragma unroll
        for (int q = 0; q < 4; ++q) { wir[q] = p0[q]; wiz[q] = p1[q]; win[q] = p2[q]; }
    }
    const float bxr = b_ih_f[j]          + b_hh_f[j];
    const float bxz = b_ih_f[Hh + j]     + b_hh_f[Hh + j];
    const float bxn = b_ih_f[2 * Hh + j];
    const float bhn = b_hh_f[2 * Hh + j];

    // per-lane LDS bases (all step offsets are compile-time immediates)
    float*       pw  = &parts[0][w][0][j];   // write base (this wave)
    const float* prd = &parts[0][0][0][j];   // read base (all waves, fixed order)

    float h = 0.0f;
    const float* xrow = x + (size_t)b * Tt * Dd;

    for (int tc = 0; tc < Tt / CH; ++tc) {
        __syncthreads();  // previous chunk fully consumed
        // stage 64 timesteps (1024 floats): one float4 per thread, coalesced
        ((float4*)xbuf)[tid] = ((const float4*)(xrow + (size_t)tc * CH * Dd))[tid];
        __syncthreads();

        // ---- input projections: wave w covers tt in [16w, 16w+16) ----
#pragma unroll 4
        for (int tt2 = 0; tt2 < KW; ++tt2) {
            const int tt = (w << 4) + tt2;
            const float4* x4 = (const float4*)(xbuf + tt * Dd);
            float4 xv0 = x4[0], xv1 = x4[1], xv2 = x4[2], xv3 = x4[3];
            float ar = bxr + dot4(wir[0], xv0) + dot4(wir[1], xv1) + dot4(wir[2], xv2) + dot4(wir[3], xv3);
            float az = bxz + dot4(wiz[0], xv0) + dot4(wiz[1], xv1) + dot4(wiz[2], xv2) + dot4(wiz[3], xv3);
            float an = bxn + dot4(win[0], xv0) + dot4(win[1], xv1) + dot4(win[2], xv2) + dot4(win[3], xv3);
            xg[0][tt][j] = ar;
            xg[1][tt][j] = az;
            xg[2][tt][j] = an;
        }
        __syncthreads();

        // ---- recurrence: K-split matvec + one barrier per step ----
        const float* xgp = &xg[0][0][j];
        float xr_n = xgp[0];
        float xz_n = xgp[CH * Hh];
        float xn_n = xgp[2 * CH * Hh];

        for (int tt = 0; tt < CH; tt += 8) {
            if (tt < CH - 8) {
                GSTEP(0, 1); GSTEP(1, 2); GSTEP(2, 3); GSTEP(3, 4);
                GSTEP(4, 5); GSTEP(5, 6); GSTEP(6, 7); GSTEP(7, 8);
            } else {
                // last block of the chunk: final prefetch clamped to row 7
                // (dead value; kept inside xg so no out-of-array access)
                GSTEP(0, 1); GSTEP(1, 2); GSTEP(2, 3); GSTEP(3, 4);
                GSTEP(4, 5); GSTEP(5, 6); GSTEP(6, 7); GSTEP(7, 7);
            }
            xgp += 8 * Hh;
        }
    }

    // ---- tail: backward single cell step + FC, wave 0 only ----
    if (w == 0) {
        float ar   = b_ih_b[j]          + b_hh_b[j];
        float az   = b_ih_b[Hh + j]     + b_hh_b[Hh + j];
        float axn  = b_ih_b[2 * Hh + j];
        float bhnb = b_hh_b[2 * Hh + j];
        {
            const float4* xl = (const float4*)(xbuf + 63 * Dd);  // t = 511
            const float4* q0 = (const float4*)(w_ih_b + (size_t)j            * Dd);
            const float4* q1 = (const float4*)(w_ih_b + (size_t)(Hh + j)     * Dd);
            const float4* q2 = (const float4*)(w_ih_b + (size_t)(2 * Hh + j) * Dd);
#pragma unroll
            for (int q = 0; q < 4; ++q) {
                float4 xv = xl[q];
                float4 a = q0[q], c = q1[q], e = q2[q];
                ar  += a.x * xv.x + a.y * xv.y + a.z * xv.z + a.w * xv.w;
                az  += c.x * xv.x + c.y * xv.y + c.z * xv.z + c.w * xv.w;
                axn += e.x * xv.x + e.y * xv.y + e.z * xv.z + e.w * xv.w;
            }
        }
        float rb = sigmoid_fast(ar);
        float zb = sigmoid_fast(az);
        float nb = tanh_fast(axn + rb * bhnb);
        float hb = (1.0f - zb) * nb;   // h0 = 0

        float v = fc_w[j] * h + fc_w[Hh + j] * hb;
#pragma unroll
        for (int off = 32; off > 0; off >>= 1)
            v += __shfl_xor(v, off, 64);
        if (j == 0) out[b] = v + fc_b[0];
    }
}

extern "C" void kernel_launch(void* const* d_in, const int* in_sizes, int n_in,
                              void* d_out, int out_size, void* d_ws, size_t ws_size,
                              hipStream_t stream) {
    const float* x      = (const float*)d_in[0];
    const float* w_ih_f = (const float*)d_in[1];
    const float* w_hh_f = (const float*)d_in[2];
    const float* b_ih_f = (const float*)d_in[3];
    const float* b_hh_f = (const float*)d_in[4];
    const float* w_ih_b = (const float*)d_in[5];
    const float* w_hh_b = (const float*)d_in[6];
    const float* b_ih_b = (const float*)d_in[7];
    const float* b_hh_b = (const float*)d_in[8];
    const float* fc_w   = (const float*)d_in[9];
    const float* fc_b   = (const float*)d_in[10];

    bigru_fused_kernel<<<dim3(Bb), dim3(NW * 64), 0, stream>>>(
        x, w_ih_f, w_hh_f, b_ih_f, b_hh_f,
        w_ih_b, w_hh_b, b_ih_b, b_hh_b, fc_w, fc_b,
        (float*)d_out);
}